// Round 1
// 154.043 us; speedup vs baseline: 1.0916x; 1.0916x over previous
//
#include <hip/hip_runtime.h>
#include <hip/hip_bf16.h>
#include <stdint.h>
#include <stddef.h>

// Problem constants (B=2, L=2048, D=32, H=8)
#define LL 2048

typedef __attribute__((ext_vector_type(8))) short short8;
typedef __attribute__((ext_vector_type(4))) float f32x4;
typedef unsigned short ushort_t;
typedef unsigned int uint_t;

// ws layout (float elements). Total ~17.9 MB.
#define VAOFF   1048576u   // V_agg f32 [bh][l][d]
#define QS16OFF 2097152u   // Q*scale*log2e bf16 [bh][l][d]
#define KS16OFF 2621440u   // K*grade_signs bf16 [bh][l][d]
#define KG16OFF 3145728u   // K raw bf16 [bh][l][d]
#define VT16OFF 3670016u   // V^T bf16 [bh*32+d][l] (key-permuted)
#define RVOFF   4194304u   // row_valid f32, B*L
#define MBOFF   4198400u   // packed mask bits [row][ks][kt], 262144 uint32
#define C2TOFF  4460544u   // cayley^T bf16 [k][ij], 32768 elems

__device__ __forceinline__ ushort_t f2bf(float f) {
    unsigned int u = __float_as_uint(f);
    u += 0x7FFFu + ((u >> 16) & 1u);   // RNE
    return (ushort_t)(u >> 16);
}
__device__ __forceinline__ float bf2f(ushort_t s) {
    return __uint_as_float(((unsigned int)s) << 16);
}
__device__ __forceinline__ uint_t pkbf(float a, float b) {   // RNE pack (one-time)
    __hip_bfloat162 h = __float22bfloat162_rn(float2{a, b});
    return *(uint_t*)&h;
}
// single-instruction bf16 pair pack (hot loops): low16 = bf16(a), high16 = bf16(b)
__device__ __forceinline__ uint_t cvtpk(float a, float b) {
    uint_t r;
    asm("v_cvt_pk_bf16_f32 %0, %1, %2" : "=v"(r) : "v"(a), "v"(b));
    return r;
}
// raw hardware exp2 (no OCML range fixup; inputs here are bounded |x| < 50)
__device__ __forceinline__ float fexp2(float x) {
#if __has_builtin(__builtin_amdgcn_exp2f)
    return __builtin_amdgcn_exp2f(x);
#else
    float r; asm("v_exp_f32 %0, %1" : "=v"(r) : "v"(x)); return r;
#endif
}

// ---------------------------------------------------------------------------
// Fused prep (r9-proven): [0,1024) mask detect+bit-pack with word order
// index = ks*16 + kt; [1024,1536) QKV 8 pos/block + direct permuted-V^T;
// [1536,1540) cayley^T bf16. Disjoint writes, input-only reads.
// ---------------------------------------------------------------------------
__global__ __launch_bounds__(256) void prep_kernel(
        const uint_t* __restrict__ mraw, uint_t* __restrict__ mb,
        const float* __restrict__ x,
        const float* __restrict__ Wq, const float* __restrict__ Wk,
        const float* __restrict__ Wv, const float* __restrict__ gs,
        const float* __restrict__ cayley, float* __restrict__ ws) {
    __shared__ float smem[8192];
    const int t = threadIdx.x;

    if (blockIdx.x < 1024) {
        int* sI = (int*)smem;
        int* sF = ((int*)smem) + 1;
        if (t == 0) { *sI = 1; *sF = 1; }
        __syncthreads();
        const size_t blk = blockIdx.x;
        const uint4* p8 = (const uint4*)(mraw + blk * 2048 + t * 8);
        const uint4 a = p8[0], c = p8[1];
        const uint_t d8[8] = {a.x, a.y, a.z, a.w, c.x, c.y, c.z, c.w};
        int oi = 1, of = 1;
#pragma unroll
        for (int i = 0; i < 8; ++i) {
            if (d8[i] > 1u) oi = 0;
            if (d8[i] != 0u && d8[i] != 0x3F800000u) of = 0;
        }
        if (!oi) atomicAnd(sI, 0);
        if (!of) atomicAnd(sF, 0);
        __syncthreads();
        const int mtype = *sI ? 1 : (*sF ? 2 : 0);
        uint_t w = 0;
        if (mtype == 0) {
#pragma unroll
            for (int i = 0; i < 8; ++i) {
#pragma unroll
                for (int by = 0; by < 4; ++by)
                    w |= (((d8[i] >> (8 * by)) & 0xFFu) ? 1u : 0u) << (i * 4 + by);
            }
        } else {
            const uint4* pi = (const uint4*)(mraw + blk * 8192 + (size_t)t * 32);
#pragma unroll
            for (int i = 0; i < 8; ++i) {
                const uint4 d = pi[i];
                if (mtype == 1) {
                    w |= (d.x << (i * 4)) | (d.y << (i * 4 + 1)) |
                         (d.z << (i * 4 + 2)) | (d.w << (i * 4 + 3));
                } else {
                    w |= ((d.x ? 1u : 0u) << (i * 4)) | ((d.y ? 1u : 0u) << (i * 4 + 1)) |
                         ((d.z ? 1u : 0u) << (i * 4 + 2)) | ((d.w ? 1u : 0u) << (i * 4 + 3));
                }
            }
        }
        const uint_t W = (uint_t)(blk * 256 + t);
        const uint_t w0 = W & 63u;
        mb[(W & ~63u) | (((w0 & 3u) << 4) | (w0 >> 2))] = w;
    } else if (blockIdx.x < 1536) {
        ushort_t* Qs16 = (ushort_t*)(ws + QS16OFF);
        ushort_t* Ks16 = (ushort_t*)(ws + KS16OFF);
        ushort_t* Kg16 = (ushort_t*)(ws + KG16OFF);
        ushort_t* Vt   = (ushort_t*)(ws + VT16OFF);
        float* sX = smem;
        const int pid0 = (blockIdx.x - 1024) * 8;
        if (t < 64) ((float4*)sX)[t] = ((const float4*)(x + (size_t)pid0 * 32))[t];
        float wq[32], wk[32], wv[32];
        const float4* wqp = (const float4*)(Wq + t * 32);
        const float4* wkp = (const float4*)(Wk + t * 32);
        const float4* wvp = (const float4*)(Wv + t * 32);
#pragma unroll
        for (int d4 = 0; d4 < 8; ++d4) {
            float4 a = wqp[d4]; wq[4*d4]=a.x; wq[4*d4+1]=a.y; wq[4*d4+2]=a.z; wq[4*d4+3]=a.w;
            float4 b = wkp[d4]; wk[4*d4]=b.x; wk[4*d4+1]=b.y; wk[4*d4+2]=b.z; wk[4*d4+3]=b.w;
            float4 c = wvp[d4]; wv[4*d4]=c.x; wv[4*d4+1]=c.y; wv[4*d4+2]=c.z; wv[4*d4+3]=c.w;
        }
        const float sgn = gs[t & 31];
        const float qscale = 0.17677669529663687f * 1.4426950408889634f;
        const int h = t >> 5, dd = t & 31;
        const int b0 = pid0 >> 11, l0 = pid0 & 2047;
        __syncthreads();
        ushort4 vt4[2];
        for (int r = 0; r < 8; ++r) {
            const int pid = pid0 + r;
            const int b = pid >> 11, l = pid & 2047;
            float q = 0.f, k = 0.f, v = 0.f;
#pragma unroll
            for (int d = 0; d < 32; ++d) {
                const float xv = sX[r * 32 + d];
                q += xv * wq[d]; k += xv * wk[d]; v += xv * wv[d];
            }
            const size_t o = ((size_t)((b * 8 + h) * 2048 + l)) * 32 + dd;
            Qs16[o] = f2bf(q * qscale);
            Ks16[o] = f2bf(k * sgn);
            Kg16[o] = f2bf(k);
            ((ushort_t*)&vt4[r >> 2])[r & 3] = f2bf(v);
        }
        ushort_t* vtrow = Vt + ((size_t)((b0 * 8 + h) * 32 + dd)) * 2048;
#pragma unroll
        for (int g4 = 0; g4 < 2; ++g4) {
            const int lg = l0 + g4 * 4;
            const int lloc = lg & 63;
            const int g = lloc >> 5, tt = (lloc >> 4) & 1, q4 = (lloc >> 2) & 3;
            const int pc = (lg & ~63) + g * 32 + q4 * 8 + tt * 4;
            *(ushort4*)(vtrow + pc) = vt4[g4];
        }
    } else {
        float* sC = smem;
        ushort_t* C2t = (ushort_t*)(ws + C2TOFF);
        const int ij0 = (blockIdx.x - 1536) * 256;   // ij in [0,1024)
#pragma unroll
        for (int i = 0; i < 8; ++i)
            ((float4*)sC)[t + i * 256] = ((const float4*)(cayley + (size_t)ij0 * 32))[t + i * 256];
        __syncthreads();
        const int k = t & 31, jc = t >> 5;
        uint_t pk[16];
#pragma unroll
        for (int j2 = 0; j2 < 16; ++j2) {
            pk[j2] = pkbf(sC[(jc * 32 + 2 * j2) * 32 + k], sC[(jc * 32 + 2 * j2 + 1) * 32 + k]);
        }
        uint_t* dst = (uint_t*)(C2t + (size_t)k * 1024 + ij0 + jc * 32);
#pragma unroll
        for (int j2 = 0; j2 < 16; ++j2) dst[j2] = pk[j2];
    }
}

// ---------------------------------------------------------------------------
// Barrier-free MFMA attention, round 11: same r10 structure (4 waves/block,
// wave = key-quarter, both Q-row halves per wave) but the softmax VALU path
// is cut ~40%: raw v_exp_f32 via __builtin_amdgcn_exp2f (drops OCML's
// range-fixup ~5 VALU/exp) and v_cvt_pk_bf16_f32 single-instruction bf16
// pair packing (drops pk2's 5 VALU/pair to 1).
// ---------------------------------------------------------------------------
__global__ __launch_bounds__(256, 4) void attn_kernel(
        const uint_t* __restrict__ mb, float* __restrict__ ws) {
    const ushort_t* Qs = (const ushort_t*)(ws + QS16OFF);
    const ushort_t* Ks = (const ushort_t*)(ws + KS16OFF);
    const ushort_t* Vt = (const ushort_t*)(ws + VT16OFF);
    float* Va = ws + VAOFF;
    float* Rv = ws + RVOFF;

    // swizzle: bh = ((bid&7)<<1)|bit9, q0 = ((bid>>3)&63)*32  (bijective)
    const int bid = blockIdx.x;
    const int bh = ((bid & 7) << 1) | ((bid >> 9) & 1);
    const int q0 = ((bid >> 3) & 63) * 32;
    const int b = bh >> 3;
    const int t = threadIdx.x;
    const int ks = t >> 6, lane = t & 63;   // wave = key-quarter
    const int quad = lane >> 4, l15 = lane & 15;

    __shared__ float accb[3][2][64][8];
    __shared__ float psL[4][32];

    // Q B-fragments for both row halves (held all loop)
    const ushort_t* qbase = Qs + ((size_t)(bh * 2048 + q0 + l15)) * 32 + quad * 8;
    const short8 qfA = *(const short8*)(qbase);
    const short8 qfB = *(const short8*)(qbase + 16 * 32);

    const ushort_t* ka_p = Ks + (size_t)bh * 65536 + (ks * 32 + l15) * 32 + quad * 8;
    const ushort_t* v0_p = Vt + (size_t)bh * 65536 + (size_t)l15 * 2048 + ks * 32 + quad * 8;
    const uint_t* m_pA = mb + ((size_t)b * 2048 + q0 + l15) * 64 + ks * 16;
    const uint_t* m_pB = m_pA + 16 * 64;

    f32x4 accA0 = {0.f, 0.f, 0.f, 0.f};
    f32x4 accA1 = {0.f, 0.f, 0.f, 0.f};
    f32x4 accA2 = {0.f, 0.f, 0.f, 0.f};
    f32x4 accB0 = {0.f, 0.f, 0.f, 0.f};
    f32x4 accB1 = {0.f, 0.f, 0.f, 0.f};
    f32x4 accB2 = {0.f, 0.f, 0.f, 0.f};
    const int bp0 = quad * 4, bp1 = 16 + quad * 4;

    union { uint_t u[4]; short8 s; } ONES;
    {
        const uint_t ov = (l15 == 0) ? 0x3F803F80u : 0u;   // bf16 1.0 pair
        ONES.u[0] = ov; ONES.u[1] = ov; ONES.u[2] = ov; ONES.u[3] = ov;
    }

#pragma unroll 2
    for (int kt = 0; kt < 16; ++kt) {
        const short8 ka = *(const short8*)(ka_p + kt * 4096);
        const short8 kb = *(const short8*)(ka_p + kt * 4096 + 512);
        const short8 v0 = *(const short8*)(v0_p + kt * 128);
        const short8 v1 = *(const short8*)(v0_p + 16 * 2048 + kt * 128);
        const uint_t mwA = m_pA[kt];
        const uint_t mwB = m_pB[kt];

        const f32x4 z = {0.f, 0.f, 0.f, 0.f};
        f32x4 s0 = __builtin_amdgcn_mfma_f32_16x16x32_bf16(ka, qfA, z, 0, 0, 0);
        f32x4 s1 = __builtin_amdgcn_mfma_f32_16x16x32_bf16(kb, qfA, z, 0, 0, 0);
        f32x4 s2 = __builtin_amdgcn_mfma_f32_16x16x32_bf16(ka, qfB, z, 0, 0, 0);
        f32x4 s3 = __builtin_amdgcn_mfma_f32_16x16x32_bf16(kb, qfB, z, 0, 0, 0);

        float pA0[4], pA1[4], pB0[4], pB1[4];
#pragma unroll
        for (int r = 0; r < 4; ++r) {
            pA0[r] = ((mwA >> (bp0 + r)) & 1u) ? fexp2(s0[r]) : 0.f;
            pA1[r] = ((mwA >> (bp1 + r)) & 1u) ? fexp2(s1[r]) : 0.f;
            pB0[r] = ((mwB >> (bp0 + r)) & 1u) ? fexp2(s2[r]) : 0.f;
            pB1[r] = ((mwB >> (bp1 + r)) & 1u) ? fexp2(s3[r]) : 0.f;
        }
        union { uint_t u[4]; short8 s; } PA, PB;
        PA.u[0] = cvtpk(pA0[0], pA0[1]); PA.u[1] = cvtpk(pA0[2], pA0[3]);
        PA.u[2] = cvtpk(pA1[0], pA1[1]); PA.u[3] = cvtpk(pA1[2], pA1[3]);
        PB.u[0] = cvtpk(pB0[0], pB0[1]); PB.u[1] = cvtpk(pB0[2], pB0[3]);
        PB.u[2] = cvtpk(pB1[0], pB1[1]); PB.u[3] = cvtpk(pB1[2], pB1[3]);

        accA0 = __builtin_amdgcn_mfma_f32_16x16x32_bf16(PA.s, v0, accA0, 0, 0, 0);
        accA1 = __builtin_amdgcn_mfma_f32_16x16x32_bf16(PA.s, v1, accA1, 0, 0, 0);
        accA2 = __builtin_amdgcn_mfma_f32_16x16x32_bf16(PA.s, ONES.s, accA2, 0, 0, 0);
        accB0 = __builtin_amdgcn_mfma_f32_16x16x32_bf16(PB.s, v0, accB0, 0, 0, 0);
        accB1 = __builtin_amdgcn_mfma_f32_16x16x32_bf16(PB.s, v1, accB1, 0, 0, 0);
        accB2 = __builtin_amdgcn_mfma_f32_16x16x32_bf16(PB.s, ONES.s, accB2, 0, 0, 0);
    }

    // partial rowsums (col-0 lanes): accA2[r] = rowsum(q-row quad*4+r)
    if (l15 == 0) {
#pragma unroll
        for (int r = 0; r < 4; ++r) {
            psL[ks][quad * 4 + r] = accA2[r];
            psL[ks][16 + quad * 4 + r] = accB2[r];
        }
    }
    if (ks != 0) {
#pragma unroll
        for (int i = 0; i < 4; ++i) {
            accb[ks - 1][0][lane][i] = accA0[i];
            accb[ks - 1][0][lane][4 + i] = accA1[i];
            accb[ks - 1][1][lane][i] = accB0[i];
            accb[ks - 1][1][lane][4 + i] = accB1[i];
        }
    }
    __syncthreads();
    if (ks == 0) {
#pragma unroll
        for (int p = 0; p < 3; ++p) {
#pragma unroll
            for (int i = 0; i < 4; ++i) {
                accA0[i] += accb[p][0][lane][i];
                accA1[i] += accb[p][0][lane][4 + i];
                accB0[i] += accb[p][1][lane][i];
                accB1[i] += accb[p][1][lane][4 + i];
            }
        }
#pragma unroll
        for (int r = 0; r < 4; ++r) {
            const int rowA = quad * 4 + r;
            const int rowB = 16 + quad * 4 + r;
            const float totA = psL[0][rowA] + psL[1][rowA] + psL[2][rowA] + psL[3][rowA];
            const float totB = psL[0][rowB] + psL[1][rowB] + psL[2][rowB] + psL[3][rowB];
            const float invA = (totA > 0.f) ? 1.0f / totA : 0.f;
            const float invB = (totB > 0.f) ? 1.0f / totB : 0.f;
            const size_t oA = ((size_t)(bh * 2048 + q0 + rowA)) * 32;
            const size_t oB = ((size_t)(bh * 2048 + q0 + rowB)) * 32;
            Va[oA + l15] = accA0[r] * invA;
            Va[oA + 16 + l15] = accA1[r] * invA;
            Va[oB + l15] = accB0[r] * invB;
            Va[oB + 16 + l15] = accB1[r] * invB;
            if ((bh & 7) == 0 && l15 == 0) {
                Rv[(size_t)b * 2048 + q0 + rowA] = (totA > 0.f) ? 1.0f : 0.f;
                Rv[(size_t)b * 2048 + q0 + rowB] = (totB > 0.f) ? 1.0f : 0.f;
            }
        }
    }
}

// ---------------------------------------------------------------------------
// MFMA geometric product + epilogue + Wo. r11 changes: F-pack via
// v_cvt_pk_bf16_f32 (1 instr/pair), and the Wo projection now reads Wo from
// LDS (staged once per block into the dead sC region, float4 XOR-swizzled so
// the d2-strided reads are ~4-way instead of 32-way serialized) — cuts the
// epilogue's L2 traffic from 256 KB/block to 32 KB/block.
// ---------------------------------------------------------------------------
__global__ __launch_bounds__(256) void gp_kernel(
        const float* __restrict__ ws, const float* __restrict__ Wo,
        float* __restrict__ out) {
    const float* Va = ws + VAOFF;
    const ushort_t* Qs = (const ushort_t*)(ws + QS16OFF);
    const ushort_t* Kg = (const ushort_t*)(ws + KG16OFF);
    const ushort_t* C2t = (const ushort_t*)(ws + C2TOFF);
    const float* Rv = ws + RVOFF;
    __shared__ ushort_t sC[32 * 1040];
    __shared__ float sH[64 * 32];

    const int t = threadIdx.x;
    const int w = t >> 6, lane = t & 63;
    const int quad = lane >> 4, l15 = lane & 15;

#pragma unroll
    for (int j = 0; j < 16; ++j) {
        const int c = j * 256 + t;
        const int row = c >> 7, col = (c & 127) * 8;
        *(short8*)(&sC[row * 1040 + col]) = *(const short8*)(C2t + row * 1024 + col);
    }

    const int grow0 = blockIdx.x * 64 + w * 16 + l15;
    const int pos = grow0 >> 3, h = grow0 & 7;
    const int b = pos >> 11, l = pos & 2047;
    const size_t gb = ((size_t)((b * 8 + h) * 2048 + l)) * 32;

    float q[32];
#pragma unroll
    for (int j8 = 0; j8 < 4; ++j8) {
        const short8 qv = *(const short8*)(Qs + gb + j8 * 8);
#pragma unroll
        for (int i = 0; i < 8; ++i) q[j8 * 8 + i] = bf2f((ushort_t)qv[i]);
    }
    float u[8];
    {
        const short8 kv = *(const short8*)(Kg + gb + quad * 8);
        const float4 va0 = *(const float4*)(Va + gb + quad * 8);
        const float4 va1 = *(const float4*)(Va + gb + quad * 8 + 4);
        u[0] = va0.x + 0.25f * bf2f((ushort_t)kv[0]);
        u[1] = va0.y + 0.25f * bf2f((ushort_t)kv[1]);
        u[2] = va0.z + 0.25f * bf2f((ushort_t)kv[2]);
        u[3] = va0.w + 0.25f * bf2f((ushort_t)kv[3]);
        u[4] = va1.x + 0.25f * bf2f((ushort_t)kv[4]);
        u[5] = va1.y + 0.25f * bf2f((ushort_t)kv[5]);
        u[6] = va1.z + 0.25f * bf2f((ushort_t)kv[6]);
        u[7] = va1.w + 0.25f * bf2f((ushort_t)kv[7]);
    }
    __syncthreads();

    f32x4 a0 = {0.f, 0.f, 0.f, 0.f};
    f32x4 a1 = {0.f, 0.f, 0.f, 0.f};
    const ushort_t* b0p = sC + (size_t)l15 * 1040 + quad * 8;
    const ushort_t* b1p = sC + (size_t)(16 + l15) * 1040 + quad * 8;

#pragma unroll
    for (int kc = 0; kc < 32; ++kc) {
        const float qk = q[kc];
        union { uint_t u4[4]; short8 s; } F;
        F.u4[0] = cvtpk(qk * u[0], qk * u[1]);
        F.u4[1] = cvtpk(qk * u[2], qk * u[3]);
        F.u4[2] = cvtpk(qk * u[4], qk * u[5]);
        F.u4[3] = cvtpk(qk * u[6], qk * u[7]);
        const short8 bb0 = *(const short8*)(b0p + kc * 32);
        const short8 bb1 = *(const short8*)(b1p + kc * 32);
        a0 = __builtin_amdgcn_mfma_f32_16x16x32_bf16(F.s, bb0, a0, 0, 0, 0);
        a1 = __builtin_amdgcn_mfma_f32_16x16x32_bf16(F.s, bb1, a1, 0, 0, 0);
    }

    // undo q scale (sqrt(32)) and the folded log2e (x ln2)
    const float SQ32 = 5.656854249492381f * 0.69314718055994531f;
#pragma unroll
    for (int r = 0; r < 4; ++r) {
        const int grow = blockIdx.x * 64 + w * 16 + quad * 4 + r;
        const int pr = grow >> 3, hr = grow & 7;
        const int br = pr >> 11, lr = pr & 2047;
        const size_t vb = ((size_t)((br * 8 + hr) * 2048 + lr)) * 32;
        const float rv = Rv[pr];
        sH[(w * 16 + quad * 4 + r) * 32 + l15] = (a0[r] * SQ32 + Va[vb + l15]) * rv;
        sH[(w * 16 + quad * 4 + r) * 32 + 16 + l15] = (a1[r] * SQ32 + Va[vb + 16 + l15]) * rv;
    }
    __syncthreads();   // all sC reads done; sH visible

    // stage Wo (32 KB) into LDS, aliasing the now-dead sC region.
    // float4 XOR swizzle: row = d2 (0..31), 64 float4 per row; dest col = j4 ^ (row&7)
    float4* sWo4 = (float4*)sC;
    {
        const float4* wog = (const float4*)Wo;
#pragma unroll
        for (int i = 0; i < 8; ++i) {
            const int f = t + i * 256;             // linear float4 idx 0..2047
            const int row = f >> 6, j4 = f & 63;
            sWo4[row * 64 + (j4 ^ (row & 7))] = wog[f];
        }
    }
    __syncthreads();

    const int pp = t >> 5, d2 = t & 31;
    const float* hp = sH + pp * 256;
    const float4* wrow = sWo4 + d2 * 64;
    const int rswz = d2 & 7;
    float o = 0.f;
#pragma unroll 8
    for (int j4 = 0; j4 < 64; ++j4) {
        const float4 wv = wrow[j4 ^ rswz];
        const float4 hv = *(const float4*)(hp + j4 * 4);
        o += wv.x * hv.x + wv.y * hv.y + wv.z * hv.z + wv.w * hv.w;
    }
    out[((size_t)blockIdx.x * 8 + pp) * 32 + d2] = o;
}

extern "C" void kernel_launch(void* const* d_in, const int* in_sizes, int n_in,
                              void* d_out, int out_size, void* d_ws, size_t ws_size,
                              hipStream_t stream) {
    const float* x      = (const float*)d_in[0];
    const void*  mask   = d_in[1];
    const float* Wq     = (const float*)d_in[2];
    const float* Wk     = (const float*)d_in[3];
    const float* Wv     = (const float*)d_in[4];
    const float* Wo     = (const float*)d_in[5];
    const float* cayley = (const float*)d_in[6];
    const float* gs     = (const float*)d_in[7];
    float* out = (float*)d_out;
    float* ws  = (float*)d_ws;
    uint_t* mb = (uint_t*)(ws + MBOFF);

    prep_kernel<<<dim3(1540), dim3(256), 0, stream>>>(
        (const uint_t*)mask, mb, x, Wq, Wk, Wv, gs, cayley, ws);
    attn_kernel<<<dim3(1024), dim3(256), 0, stream>>>(mb, ws);
    gp_kernel<<<dim3(512), dim3(256), 0, stream>>>(ws, Wo, out);
}

// Round 2
// 152.279 us; speedup vs baseline: 1.1043x; 1.0116x over previous
//
#include <hip/hip_runtime.h>
#include <hip/hip_bf16.h>
#include <stdint.h>
#include <stddef.h>

// Problem constants (B=2, L=2048, D=32, H=8)
#define LL 2048

typedef __attribute__((ext_vector_type(8))) short short8;
typedef __attribute__((ext_vector_type(4))) float f32x4;
typedef unsigned short ushort_t;
typedef unsigned int uint_t;

// ws layout (float elements). Total ~17.9 MB.
#define VAOFF   1048576u   // V_agg f32 [bh][l][d]
#define QS16OFF 2097152u   // Q*scale*log2e bf16 [bh][l][d]
#define KG16OFF 3145728u   // K raw bf16 [bh][l][d]  (attn applies gs via Q sign-flip)
#define VT16OFF 3670016u   // V^T bf16 [bh*32+d][l] (key-permuted)
#define RVOFF   4194304u   // row_valid f32, B*L
#define MBOFF   4198400u   // packed mask bits [row][ks][kt], 262144 uint32
#define C2TOFF  4460544u   // cayley^T bf16 [k][ij], 32768 elems

__device__ __forceinline__ ushort_t f2bf(float f) {
    unsigned int u = __float_as_uint(f);
    u += 0x7FFFu + ((u >> 16) & 1u);   // RNE
    return (ushort_t)(u >> 16);
}
__device__ __forceinline__ float bf2f(ushort_t s) {
    return __uint_as_float(((unsigned int)s) << 16);
}
__device__ __forceinline__ uint_t pkbf(float a, float b) {   // RNE pack (one-time)
    __hip_bfloat162 h = __float22bfloat162_rn(float2{a, b});
    return *(uint_t*)&h;
}
// single-instruction bf16 pair pack (hot loops): low16 = bf16(a), high16 = bf16(b)
__device__ __forceinline__ uint_t cvtpk(float a, float b) {
    uint_t r;
    asm("v_cvt_pk_bf16_f32 %0, %1, %2" : "=v"(r) : "v"(a), "v"(b));
    return r;
}
// raw hardware exp2 (no OCML range fixup; inputs here are bounded)
__device__ __forceinline__ float fexp2(float x) {
#if __has_builtin(__builtin_amdgcn_exp2f)
    return __builtin_amdgcn_exp2f(x);
#else
    float r; asm("v_exp_f32 %0, %1" : "=v"(r) : "v"(x)); return r;
#endif
}

// ---------------------------------------------------------------------------
// Fused prep: [0,1024) mask detect+bit-pack with word order index = ks*16+kt;
// [1024,1536) QKV 8 pos/block + direct permuted-V^T; [1536,1540) cayley^T.
// r12: no Ks16 (gs folded into attn's Q regs); __all instead of LDS atomics.
// ---------------------------------------------------------------------------
__global__ __launch_bounds__(256) void prep_kernel(
        const uint_t* __restrict__ mraw, uint_t* __restrict__ mb,
        const float* __restrict__ x,
        const float* __restrict__ Wq, const float* __restrict__ Wk,
        const float* __restrict__ Wv,
        const float* __restrict__ cayley, float* __restrict__ ws) {
    __shared__ float smem[8192];
    const int t = threadIdx.x;

    if (blockIdx.x < 1024) {
        int* sI = (int*)smem;
        int* sF = ((int*)smem) + 1;
        if (t == 0) { *sI = 1; *sF = 1; }
        __syncthreads();
        const size_t blk = blockIdx.x;
        const uint4* p8 = (const uint4*)(mraw + blk * 2048 + t * 8);
        const uint4 a = p8[0], c = p8[1];
        const uint_t d8[8] = {a.x, a.y, a.z, a.w, c.x, c.y, c.z, c.w};
        int oi = 1, of = 1;
#pragma unroll
        for (int i = 0; i < 8; ++i) {
            if (d8[i] > 1u) oi = 0;
            if (d8[i] != 0u && d8[i] != 0x3F800000u) of = 0;
        }
        const int ai = __all(oi), af = __all(of);
        if ((t & 63) == 0) {
            if (!ai) *sI = 0;
            if (!af) *sF = 0;
        }
        __syncthreads();
        const int mtype = *sI ? 1 : (*sF ? 2 : 0);
        uint_t w = 0;
        if (mtype == 0) {
#pragma unroll
            for (int i = 0; i < 8; ++i) {
#pragma unroll
                for (int by = 0; by < 4; ++by)
                    w |= (((d8[i] >> (8 * by)) & 0xFFu) ? 1u : 0u) << (i * 4 + by);
            }
        } else {
            const uint4* pi = (const uint4*)(mraw + blk * 8192 + (size_t)t * 32);
#pragma unroll
            for (int i = 0; i < 8; ++i) {
                const uint4 d = pi[i];
                if (mtype == 1) {
                    w |= (d.x << (i * 4)) | (d.y << (i * 4 + 1)) |
                         (d.z << (i * 4 + 2)) | (d.w << (i * 4 + 3));
                } else {
                    w |= ((d.x ? 1u : 0u) << (i * 4)) | ((d.y ? 1u : 0u) << (i * 4 + 1)) |
                         ((d.z ? 1u : 0u) << (i * 4 + 2)) | ((d.w ? 1u : 0u) << (i * 4 + 3));
                }
            }
        }
        const uint_t W = (uint_t)(blk * 256 + t);
        const uint_t w0 = W & 63u;
        mb[(W & ~63u) | (((w0 & 3u) << 4) | (w0 >> 2))] = w;
    } else if (blockIdx.x < 1536) {
        ushort_t* Qs16 = (ushort_t*)(ws + QS16OFF);
        ushort_t* Kg16 = (ushort_t*)(ws + KG16OFF);
        ushort_t* Vt   = (ushort_t*)(ws + VT16OFF);
        float* sX = smem;
        const int pid0 = (blockIdx.x - 1024) * 8;
        if (t < 64) ((float4*)sX)[t] = ((const float4*)(x + (size_t)pid0 * 32))[t];
        float wq[32], wk[32], wv[32];
        const float4* wqp = (const float4*)(Wq + t * 32);
        const float4* wkp = (const float4*)(Wk + t * 32);
        const float4* wvp = (const float4*)(Wv + t * 32);
#pragma unroll
        for (int d4 = 0; d4 < 8; ++d4) {
            float4 a = wqp[d4]; wq[4*d4]=a.x; wq[4*d4+1]=a.y; wq[4*d4+2]=a.z; wq[4*d4+3]=a.w;
            float4 b = wkp[d4]; wk[4*d4]=b.x; wk[4*d4+1]=b.y; wk[4*d4+2]=b.z; wk[4*d4+3]=b.w;
            float4 c = wvp[d4]; wv[4*d4]=c.x; wv[4*d4+1]=c.y; wv[4*d4+2]=c.z; wv[4*d4+3]=c.w;
        }
        const float qscale = 0.17677669529663687f * 1.4426950408889634f;
        const int h = t >> 5, dd = t & 31;
        const int b0 = pid0 >> 11, l0 = pid0 & 2047;
        __syncthreads();
        ushort4 vt4[2];
        for (int r = 0; r < 8; ++r) {
            const int pid = pid0 + r;
            const int b = pid >> 11, l = pid & 2047;
            float q = 0.f, k = 0.f, v = 0.f;
#pragma unroll
            for (int d = 0; d < 32; ++d) {
                const float xv = sX[r * 32 + d];
                q += xv * wq[d]; k += xv * wk[d]; v += xv * wv[d];
            }
            const size_t o = ((size_t)((b * 8 + h) * 2048 + l)) * 32 + dd;
            Qs16[o] = f2bf(q * qscale);
            Kg16[o] = f2bf(k);
            ((ushort_t*)&vt4[r >> 2])[r & 3] = f2bf(v);
        }
        ushort_t* vtrow = Vt + ((size_t)((b0 * 8 + h) * 32 + dd)) * 2048;
#pragma unroll
        for (int g4 = 0; g4 < 2; ++g4) {
            const int lg = l0 + g4 * 4;
            const int lloc = lg & 63;
            const int g = lloc >> 5, tt = (lloc >> 4) & 1, q4 = (lloc >> 2) & 3;
            const int pc = (lg & ~63) + g * 32 + q4 * 8 + tt * 4;
            *(ushort4*)(vtrow + pc) = vt4[g4];
        }
    } else {
        float* sC = smem;
        ushort_t* C2t = (ushort_t*)(ws + C2TOFF);
        const int ij0 = (blockIdx.x - 1536) * 256;   // ij in [0,1024)
#pragma unroll
        for (int i = 0; i < 8; ++i)
            ((float4*)sC)[t + i * 256] = ((const float4*)(cayley + (size_t)ij0 * 32))[t + i * 256];
        __syncthreads();
        const int k = t & 31, jc = t >> 5;
        uint_t pk[16];
#pragma unroll
        for (int j2 = 0; j2 < 16; ++j2) {
            pk[j2] = pkbf(sC[(jc * 32 + 2 * j2) * 32 + k], sC[(jc * 32 + 2 * j2 + 1) * 32 + k]);
        }
        uint_t* dst = (uint_t*)(C2t + (size_t)k * 1024 + ij0 + jc * 32);
#pragma unroll
        for (int j2 = 0; j2 < 16; ++j2) dst[j2] = pk[j2];
    }
}

// ---------------------------------------------------------------------------
// MFMA attention, round 12: mask applied as bit-AND on the packed bf16 P
// words via a 16-entry LDS LUT (4 bfe + 4 ds_read_b64 + 8 v_and per iter,
// replacing 48 cmp/cndmask VALU). grade_signs folded into the Q register
// fragments as sign-bit XORs (one-time), so K is read from the single raw
// Kg buffer. exp2 runs unconditionally; masked lanes are ANDed to +0.
// ---------------------------------------------------------------------------
__global__ __launch_bounds__(256, 4) void attn_kernel(
        const uint_t* __restrict__ mb, float* __restrict__ ws,
        const float* __restrict__ gs) {
    const ushort_t* Qs = (const ushort_t*)(ws + QS16OFF);
    const ushort_t* Kg = (const ushort_t*)(ws + KG16OFF);
    const ushort_t* Vt = (const ushort_t*)(ws + VT16OFF);
    float* Va = ws + VAOFF;
    float* Rv = ws + RVOFF;

    // swizzle: bh = ((bid&7)<<1)|bit9, q0 = ((bid>>3)&63)*32  (bijective)
    const int bid = blockIdx.x;
    const int bh = ((bid & 7) << 1) | ((bid >> 9) & 1);
    const int q0 = ((bid >> 3) & 63) * 32;
    const int b = bh >> 3;
    const int t = threadIdx.x;
    const int ks = t >> 6, lane = t & 63;   // wave = key-quarter
    const int quad = lane >> 4, l15 = lane & 15;

    __shared__ float accb[3][2][64][8];
    __shared__ float psL[4][32];
    __shared__ uint2 mlut[16];

    if (t < 16) {
        const uint_t lo = ((t & 1) ? 0xFFFFu : 0u) | ((t & 2) ? 0xFFFF0000u : 0u);
        const uint_t hi = ((t & 4) ? 0xFFFFu : 0u) | ((t & 8) ? 0xFFFF0000u : 0u);
        mlut[t] = uint2{lo, hi};
    }

    // Q B-fragments for both row halves (held all loop); fold grade signs
    // (±1) into Q via sign-bit XOR per d position.
    const ushort_t* qbase = Qs + ((size_t)(bh * 2048 + q0 + l15)) * 32 + quad * 8;
    union { uint_t u[4]; short8 s; } QA, QB;
    QA.s = *(const short8*)(qbase);
    QB.s = *(const short8*)(qbase + 16 * 32);
#pragma unroll
    for (int i = 0; i < 4; ++i) {
        const uint_t xlo = (gs[quad * 8 + 2 * i]     < 0.f) ? 0x00008000u : 0u;
        const uint_t xhi = (gs[quad * 8 + 2 * i + 1] < 0.f) ? 0x80000000u : 0u;
        const uint_t xo = xlo | xhi;
        QA.u[i] ^= xo; QB.u[i] ^= xo;
    }

    const ushort_t* ka_p = Kg + (size_t)bh * 65536 + (ks * 32 + l15) * 32 + quad * 8;
    const ushort_t* v0_p = Vt + (size_t)bh * 65536 + (size_t)l15 * 2048 + ks * 32 + quad * 8;
    const uint_t* m_pA = mb + ((size_t)b * 2048 + q0 + l15) * 64 + ks * 16;
    const uint_t* m_pB = m_pA + 16 * 64;

    f32x4 accA0 = {0.f, 0.f, 0.f, 0.f};
    f32x4 accA1 = {0.f, 0.f, 0.f, 0.f};
    f32x4 accA2 = {0.f, 0.f, 0.f, 0.f};
    f32x4 accB0 = {0.f, 0.f, 0.f, 0.f};
    f32x4 accB1 = {0.f, 0.f, 0.f, 0.f};
    f32x4 accB2 = {0.f, 0.f, 0.f, 0.f};
    const int bp0 = quad * 4, bp1 = 16 + quad * 4;

    union { uint_t u[4]; short8 s; } ONES;
    {
        const uint_t ov = (l15 == 0) ? 0x3F803F80u : 0u;   // bf16 1.0 pair
        ONES.u[0] = ov; ONES.u[1] = ov; ONES.u[2] = ov; ONES.u[3] = ov;
    }
    __syncthreads();   // mlut visible

#pragma unroll 2
    for (int kt = 0; kt < 16; ++kt) {
        const short8 ka = *(const short8*)(ka_p + kt * 4096);
        const short8 kb = *(const short8*)(ka_p + kt * 4096 + 512);
        const short8 v0 = *(const short8*)(v0_p + kt * 128);
        const short8 v1 = *(const short8*)(v0_p + 16 * 2048 + kt * 128);
        const uint_t mwA = m_pA[kt];
        const uint_t mwB = m_pB[kt];

        const f32x4 z = {0.f, 0.f, 0.f, 0.f};
        f32x4 s0 = __builtin_amdgcn_mfma_f32_16x16x32_bf16(ka, QA.s, z, 0, 0, 0);
        f32x4 s1 = __builtin_amdgcn_mfma_f32_16x16x32_bf16(kb, QA.s, z, 0, 0, 0);
        f32x4 s2 = __builtin_amdgcn_mfma_f32_16x16x32_bf16(ka, QB.s, z, 0, 0, 0);
        f32x4 s3 = __builtin_amdgcn_mfma_f32_16x16x32_bf16(kb, QB.s, z, 0, 0, 0);

        const uint2 mA0 = mlut[(mwA >> bp0) & 15u];
        const uint2 mA1 = mlut[(mwA >> bp1) & 15u];
        const uint2 mB0 = mlut[(mwB >> bp0) & 15u];
        const uint2 mB1 = mlut[(mwB >> bp1) & 15u];

        float eA0[4], eA1[4], eB0[4], eB1[4];
#pragma unroll
        for (int r = 0; r < 4; ++r) {
            eA0[r] = fexp2(s0[r]);
            eA1[r] = fexp2(s1[r]);
            eB0[r] = fexp2(s2[r]);
            eB1[r] = fexp2(s3[r]);
        }
        union { uint_t u[4]; short8 s; } PA, PB;
        PA.u[0] = cvtpk(eA0[0], eA0[1]) & mA0.x;
        PA.u[1] = cvtpk(eA0[2], eA0[3]) & mA0.y;
        PA.u[2] = cvtpk(eA1[0], eA1[1]) & mA1.x;
        PA.u[3] = cvtpk(eA1[2], eA1[3]) & mA1.y;
        PB.u[0] = cvtpk(eB0[0], eB0[1]) & mB0.x;
        PB.u[1] = cvtpk(eB0[2], eB0[3]) & mB0.y;
        PB.u[2] = cvtpk(eB1[0], eB1[1]) & mB1.x;
        PB.u[3] = cvtpk(eB1[2], eB1[3]) & mB1.y;

        accA0 = __builtin_amdgcn_mfma_f32_16x16x32_bf16(PA.s, v0, accA0, 0, 0, 0);
        accA1 = __builtin_amdgcn_mfma_f32_16x16x32_bf16(PA.s, v1, accA1, 0, 0, 0);
        accA2 = __builtin_amdgcn_mfma_f32_16x16x32_bf16(PA.s, ONES.s, accA2, 0, 0, 0);
        accB0 = __builtin_amdgcn_mfma_f32_16x16x32_bf16(PB.s, v0, accB0, 0, 0, 0);
        accB1 = __builtin_amdgcn_mfma_f32_16x16x32_bf16(PB.s, v1, accB1, 0, 0, 0);
        accB2 = __builtin_amdgcn_mfma_f32_16x16x32_bf16(PB.s, ONES.s, accB2, 0, 0, 0);
    }

    // partial rowsums (col-0 lanes): accA2[r] = rowsum(q-row quad*4+r)
    if (l15 == 0) {
#pragma unroll
        for (int r = 0; r < 4; ++r) {
            psL[ks][quad * 4 + r] = accA2[r];
            psL[ks][16 + quad * 4 + r] = accB2[r];
        }
    }
    if (ks != 0) {
#pragma unroll
        for (int i = 0; i < 4; ++i) {
            accb[ks - 1][0][lane][i] = accA0[i];
            accb[ks - 1][0][lane][4 + i] = accA1[i];
            accb[ks - 1][1][lane][i] = accB0[i];
            accb[ks - 1][1][lane][4 + i] = accB1[i];
        }
    }
    __syncthreads();
    if (ks == 0) {
#pragma unroll
        for (int p = 0; p < 3; ++p) {
#pragma unroll
            for (int i = 0; i < 4; ++i) {
                accA0[i] += accb[p][0][lane][i];
                accA1[i] += accb[p][0][lane][4 + i];
                accB0[i] += accb[p][1][lane][i];
                accB1[i] += accb[p][1][lane][4 + i];
            }
        }
#pragma unroll
        for (int r = 0; r < 4; ++r) {
            const int rowA = quad * 4 + r;
            const int rowB = 16 + quad * 4 + r;
            const float totA = psL[0][rowA] + psL[1][rowA] + psL[2][rowA] + psL[3][rowA];
            const float totB = psL[0][rowB] + psL[1][rowB] + psL[2][rowB] + psL[3][rowB];
            const float invA = (totA > 0.f) ? 1.0f / totA : 0.f;
            const float invB = (totB > 0.f) ? 1.0f / totB : 0.f;
            const size_t oA = ((size_t)(bh * 2048 + q0 + rowA)) * 32;
            const size_t oB = ((size_t)(bh * 2048 + q0 + rowB)) * 32;
            Va[oA + l15] = accA0[r] * invA;
            Va[oA + 16 + l15] = accA1[r] * invA;
            Va[oB + l15] = accB0[r] * invB;
            Va[oB + 16 + l15] = accB1[r] * invB;
            if ((bh & 7) == 0 && l15 == 0) {
                Rv[(size_t)b * 2048 + q0 + rowA] = (totA > 0.f) ? 1.0f : 0.f;
                Rv[(size_t)b * 2048 + q0 + rowB] = (totB > 0.f) ? 1.0f : 0.f;
            }
        }
    }
}

// ---------------------------------------------------------------------------
// MFMA geometric product + epilogue + Wo (r11-proven: cvt_pk F-pack, Wo
// staged in LDS with float4 XOR swizzle, sC stride 1040 ushorts).
// ---------------------------------------------------------------------------
__global__ __launch_bounds__(256) void gp_kernel(
        const float* __restrict__ ws, const float* __restrict__ Wo,
        float* __restrict__ out) {
    const float* Va = ws + VAOFF;
    const ushort_t* Qs = (const ushort_t*)(ws + QS16OFF);
    const ushort_t* Kg = (const ushort_t*)(ws + KG16OFF);
    const ushort_t* C2t = (const ushort_t*)(ws + C2TOFF);
    const float* Rv = ws + RVOFF;
    __shared__ ushort_t sC[32 * 1040];
    __shared__ float sH[64 * 32];

    const int t = threadIdx.x;
    const int w = t >> 6, lane = t & 63;
    const int quad = lane >> 4, l15 = lane & 15;

#pragma unroll
    for (int j = 0; j < 16; ++j) {
        const int c = j * 256 + t;
        const int row = c >> 7, col = (c & 127) * 8;
        *(short8*)(&sC[row * 1040 + col]) = *(const short8*)(C2t + row * 1024 + col);
    }

    const int grow0 = blockIdx.x * 64 + w * 16 + l15;
    const int pos = grow0 >> 3, h = grow0 & 7;
    const int b = pos >> 11, l = pos & 2047;
    const size_t gb = ((size_t)((b * 8 + h) * 2048 + l)) * 32;

    float q[32];
#pragma unroll
    for (int j8 = 0; j8 < 4; ++j8) {
        const short8 qv = *(const short8*)(Qs + gb + j8 * 8);
#pragma unroll
        for (int i = 0; i < 8; ++i) q[j8 * 8 + i] = bf2f((ushort_t)qv[i]);
    }
    float u[8];
    {
        const short8 kv = *(const short8*)(Kg + gb + quad * 8);
        const float4 va0 = *(const float4*)(Va + gb + quad * 8);
        const float4 va1 = *(const float4*)(Va + gb + quad * 8 + 4);
        u[0] = va0.x + 0.25f * bf2f((ushort_t)kv[0]);
        u[1] = va0.y + 0.25f * bf2f((ushort_t)kv[1]);
        u[2] = va0.z + 0.25f * bf2f((ushort_t)kv[2]);
        u[3] = va0.w + 0.25f * bf2f((ushort_t)kv[3]);
        u[4] = va1.x + 0.25f * bf2f((ushort_t)kv[4]);
        u[5] = va1.y + 0.25f * bf2f((ushort_t)kv[5]);
        u[6] = va1.z + 0.25f * bf2f((ushort_t)kv[6]);
        u[7] = va1.w + 0.25f * bf2f((ushort_t)kv[7]);
    }
    __syncthreads();

    f32x4 a0 = {0.f, 0.f, 0.f, 0.f};
    f32x4 a1 = {0.f, 0.f, 0.f, 0.f};
    const ushort_t* b0p = sC + (size_t)l15 * 1040 + quad * 8;
    const ushort_t* b1p = sC + (size_t)(16 + l15) * 1040 + quad * 8;

#pragma unroll
    for (int kc = 0; kc < 32; ++kc) {
        const float qk = q[kc];
        union { uint_t u4[4]; short8 s; } F;
        F.u4[0] = cvtpk(qk * u[0], qk * u[1]);
        F.u4[1] = cvtpk(qk * u[2], qk * u[3]);
        F.u4[2] = cvtpk(qk * u[4], qk * u[5]);
        F.u4[3] = cvtpk(qk * u[6], qk * u[7]);
        const short8 bb0 = *(const short8*)(b0p + kc * 32);
        const short8 bb1 = *(const short8*)(b1p + kc * 32);
        a0 = __builtin_amdgcn_mfma_f32_16x16x32_bf16(F.s, bb0, a0, 0, 0, 0);
        a1 = __builtin_amdgcn_mfma_f32_16x16x32_bf16(F.s, bb1, a1, 0, 0, 0);
    }

    // undo q scale (sqrt(32)) and the folded log2e (x ln2)
    const float SQ32 = 5.656854249492381f * 0.69314718055994531f;
#pragma unroll
    for (int r = 0; r < 4; ++r) {
        const int grow = blockIdx.x * 64 + w * 16 + quad * 4 + r;
        const int pr = grow >> 3, hr = grow & 7;
        const int br = pr >> 11, lr = pr & 2047;
        const size_t vb = ((size_t)((br * 8 + hr) * 2048 + lr)) * 32;
        const float rv = Rv[pr];
        sH[(w * 16 + quad * 4 + r) * 32 + l15] = (a0[r] * SQ32 + Va[vb + l15]) * rv;
        sH[(w * 16 + quad * 4 + r) * 32 + 16 + l15] = (a1[r] * SQ32 + Va[vb + 16 + l15]) * rv;
    }
    __syncthreads();   // all sC reads done; sH visible

    // stage Wo (32 KB) into LDS, aliasing the now-dead sC region.
    float4* sWo4 = (float4*)sC;
    {
        const float4* wog = (const float4*)Wo;
#pragma unroll
        for (int i = 0; i < 8; ++i) {
            const int f = t + i * 256;             // linear float4 idx 0..2047
            const int row = f >> 6, j4 = f & 63;
            sWo4[row * 64 + (j4 ^ (row & 7))] = wog[f];
        }
    }
    __syncthreads();

    const int pp = t >> 5, d2 = t & 31;
    const float* hp = sH + pp * 256;
    const float4* wrow = sWo4 + d2 * 64;
    const int rswz = d2 & 7;
    float o = 0.f;
#pragma unroll 8
    for (int j4 = 0; j4 < 64; ++j4) {
        const float4 wv = wrow[j4 ^ rswz];
        const float4 hv = *(const float4*)(hp + j4 * 4);
        o += wv.x * hv.x + wv.y * hv.y + wv.z * hv.z + wv.w * hv.w;
    }
    out[((size_t)blockIdx.x * 8 + pp) * 32 + d2] = o;
}

extern "C" void kernel_launch(void* const* d_in, const int* in_sizes, int n_in,
                              void* d_out, int out_size, void* d_ws, size_t ws_size,
                              hipStream_t stream) {
    const float* x      = (const float*)d_in[0];
    const void*  mask   = d_in[1];
    const float* Wq     = (const float*)d_in[2];
    const float* Wk     = (const float*)d_in[3];
    const float* Wv     = (const float*)d_in[4];
    const float* Wo     = (const float*)d_in[5];
    const float* cayley = (const float*)d_in[6];
    const float* gs     = (const float*)d_in[7];
    float* out = (float*)d_out;
    float* ws  = (float*)d_ws;
    uint_t* mb = (uint_t*)(ws + MBOFF);

    prep_kernel<<<dim3(1540), dim3(256), 0, stream>>>(
        (const uint_t*)mask, mb, x, Wq, Wk, Wv, cayley, ws);
    attn_kernel<<<dim3(1024), dim3(256), 0, stream>>>(mb, ws, gs);
    gp_kernel<<<dim3(512), dim3(256), 0, stream>>>(ws, Wo, out);
}